// Round 1
// baseline (446.434 us; speedup 1.0000x reference)
//
#include <hip/hip_runtime.h>

// CacheFuser on MI355X (gfx950).
// Strategy: prep kernel transposes+casts all weights to bf16 W^T[p][k] (k-contig)
// into d_ws; one fused kernel per (layer, 128-row tile) does the whole chain
// (align x4 sharers -> ew-weighted agg via MFMA C-chaining -> concat-fuse MLP
// -> gated residual) with mfma_f32_16x16x32_bf16, f32 accumulation.
// Layout robustness: A and B fragments use the SAME k-slice mapping, so any
// internal MFMA k-slot permutation cancels in the contraction.

typedef unsigned int  u32;
typedef unsigned short u16;
typedef __attribute__((ext_vector_type(8))) short bf16x8;   // 8 x bf16 = 4 VGPR
typedef __attribute__((ext_vector_type(4))) float f32x4;    // 4 x f32

#define LL   8
#define NN   4
#define HH   256
#define RPL  8192            // rows per layer = B*S
#define BM   128             // rows per block
#define WST  40              // padded LDS stride (u16) for W/X k-tiles

// d_ws layout (u16 elements): transposed bf16 weights, [L][P=256][K] row-major
#define OFF_AKW1 0u
#define OFF_AKW2 524288u
#define OFF_AVW1 1048576u
#define OFF_AVW2 1572864u
#define OFF_FKW1 2097152u    // K=512
#define OFF_FKW2 3145728u
#define OFF_FVW1 3670016u    // K=512
#define OFF_FVW2 4718592u
// total: 5242880 u16 = 10485760 bytes needed in d_ws

__device__ __forceinline__ u16 f2bf(float f) {
  u32 u = __builtin_bit_cast(u32, f);
  u32 r = (u + 0x7fffu + ((u >> 16) & 1u)) >> 16;   // round-to-nearest-even
  return (u16)r;
}

// ---------------- prep: W[k][p] f32 -> W^T[p][k] bf16 (32x32 LDS transpose) ---
__global__ __launch_bounds__(256) void prep_wt_k(
    const float* __restrict__ s0, const float* __restrict__ s1,
    const float* __restrict__ s2, const float* __restrict__ s3,
    const float* __restrict__ s4, const float* __restrict__ s5,
    const float* __restrict__ s6, const float* __restrict__ s7,
    u16* __restrict__ wt)
{
  __shared__ float tile[32][33];
  const int mat = blockIdx.z, l = blockIdx.y, t = blockIdx.x;
  const float* src; size_t off; int K;
  switch (mat) {
    case 0: src = s0; off = OFF_AKW1; K = 256; break;
    case 1: src = s1; off = OFF_AKW2; K = 256; break;
    case 2: src = s2; off = OFF_AVW1; K = 256; break;
    case 3: src = s3; off = OFF_AVW2; K = 256; break;
    case 4: src = s4; off = OFF_FKW1; K = 512; break;
    case 5: src = s5; off = OFF_FKW2; K = 256; break;
    case 6: src = s6; off = OFF_FVW1; K = 512; break;
    default: src = s7; off = OFF_FVW2; K = 256; break;
  }
  const int ntk = K >> 5;
  if (t >= ntk * 8) return;                 // P/32 = 8
  const int tk = t % ntk, tp = t / ntk;
  src += (size_t)l * K * HH;
  u16* dst = wt + off + (size_t)l * HH * K;
  #pragma unroll
  for (int i = 0; i < 4; ++i) {
    int idx = threadIdx.x + i * 256;
    int r = idx >> 5, c = idx & 31;
    tile[r][c] = src[(size_t)(tk * 32 + r) * HH + tp * 32 + c];
  }
  __syncthreads();
  #pragma unroll
  for (int i = 0; i < 4; ++i) {
    int idx = threadIdx.x + i * 256;
    int r = idx >> 5, c = idx & 31;
    dst[(size_t)(tp * 32 + r) * K + tk * 32 + c] = f2bf(tile[c][r]);
  }
}

// ---------------- main kernel helpers ---------------------------------------
__device__ __forceinline__ void zero44(f32x4 (&a)[4][4]) {
  f32x4 z = {0.f, 0.f, 0.f, 0.f};
  #pragma unroll
  for (int i = 0; i < 4; ++i)
    #pragma unroll
    for (int j = 0; j < 4; ++j) a[i][j] = z;
}

// One K=256 pass (8 ksteps of 32): D[p][q] += W^T[p][k] * Act[q][k].
// STREAM: Act comes from global f32 (row stride HH), staged+cast per kstep.
// !STREAM: Act comes from a swizzled [BM][256] bf16 LDS buffer.
template<bool STREAM>
__device__ __forceinline__ void gemm_block(
    f32x4 (&acc)[4][4],
    const u16* __restrict__ wtRow, int wstride,
    const float* __restrict__ act, const u16* __restrict__ ldsAct,
    u16* sW, u16* sX,
    int tid, int wp, int wq, int lr, int g)
{
  #pragma unroll 1
  for (int kt = 0; kt < 8; ++kt) {
    // ---- stage W^T k-tile [256][32] (+X tile if streaming), loads hoisted ----
    const int c0 = tid, c1 = 512 + tid;
    const int p0s = c0 >> 2, j0 = c0 & 3;
    const int p1s = c1 >> 2, j1 = c1 & 3;
    uint4 wv0 = *(const uint4*)(wtRow + (size_t)p0s * wstride + kt * 32 + j0 * 8);
    uint4 wv1 = *(const uint4*)(wtRow + (size_t)p1s * wstride + kt * 32 + j1 * 8);
    float4 xv0, xv1; int q0s = 0, jx0 = 0, q1s = 0, jx1 = 0;
    if (STREAM) {
      q0s = c0 >> 3; jx0 = c0 & 7;
      q1s = c1 >> 3; jx1 = c1 & 7;
      xv0 = *(const float4*)(act + (size_t)q0s * HH + kt * 32 + jx0 * 4);
      xv1 = *(const float4*)(act + (size_t)q1s * HH + kt * 32 + jx1 * 4);
    }
    *(uint4*)(sW + p0s * WST + j0 * 8) = wv0;
    *(uint4*)(sW + p1s * WST + j1 * 8) = wv1;
    if (STREAM) {
      ushort4 o0, o1;
      o0.x = f2bf(xv0.x); o0.y = f2bf(xv0.y); o0.z = f2bf(xv0.z); o0.w = f2bf(xv0.w);
      o1.x = f2bf(xv1.x); o1.y = f2bf(xv1.y); o1.z = f2bf(xv1.z); o1.w = f2bf(xv1.w);
      *(ushort4*)(sX + q0s * WST + jx0 * 4) = o0;
      *(ushort4*)(sX + q1s * WST + jx1 * 4) = o1;
    }
    __syncthreads();
    // ---- fragments + 16 MFMA ----
    bf16x8 a[4], b[4];
    #pragma unroll
    for (int fp = 0; fp < 4; ++fp) {
      int p = wp * 64 + fp * 16 + lr;
      a[fp] = *(const bf16x8*)(sW + p * WST + g * 8);
    }
    #pragma unroll
    for (int fq = 0; fq < 4; ++fq) {
      int q = wq * 64 + fq * 16 + lr;
      if (STREAM) {
        b[fq] = *(const bf16x8*)(sX + q * WST + g * 8);
      } else {
        int k = (kt * 32 + g * 8) ^ ((q & 7) << 3);
        b[fq] = *(const bf16x8*)(ldsAct + q * HH + k);
      }
    }
    #pragma unroll
    for (int fp = 0; fp < 4; ++fp)
      #pragma unroll
      for (int fq = 0; fq < 4; ++fq)
        acc[fp][fq] = __builtin_amdgcn_mfma_f32_16x16x32_bf16(a[fp], b[fq], acc[fp][fq], 0, 0, 0);
    __syncthreads();
  }
}

// acc -> bf16 swizzled LDS buffer: v = [relu?]( acc + bscale*bias ) * post
__device__ __forceinline__ void epi_store(
    u16* buf, f32x4 (&acc)[4][4], const float* __restrict__ bias,
    float bscale, float post, bool doRelu, int wp, int wq, int lr, int g)
{
  #pragma unroll
  for (int fp = 0; fp < 4; ++fp) {
    int p0 = wp * 64 + fp * 16 + g * 4;
    float4 bv = *(const float4*)(bias + p0);
    #pragma unroll
    for (int fq = 0; fq < 4; ++fq) {
      int q = wq * 64 + fq * 16 + lr;
      float v0 = acc[fp][fq][0] + bscale * bv.x;
      float v1 = acc[fp][fq][1] + bscale * bv.y;
      float v2 = acc[fp][fq][2] + bscale * bv.z;
      float v3 = acc[fp][fq][3] + bscale * bv.w;
      if (doRelu) {
        v0 = fmaxf(v0, 0.f); v1 = fmaxf(v1, 0.f);
        v2 = fmaxf(v2, 0.f); v3 = fmaxf(v3, 0.f);
      }
      ushort4 o;
      o.x = f2bf(v0 * post); o.y = f2bf(v1 * post);
      o.z = f2bf(v2 * post); o.w = f2bf(v3 * post);
      *(ushort4*)(buf + q * HH + (p0 ^ ((q & 7) << 3))) = o;
    }
  }
}

// out = recv + gate*(acc + bias), f32, packed float4 stores
__device__ __forceinline__ void epi_out(
    f32x4 (&acc)[4][4], const float* __restrict__ bias,
    const float* __restrict__ recv, float* __restrict__ outp,
    float gate, int wp, int wq, int lr, int g)
{
  #pragma unroll
  for (int fp = 0; fp < 4; ++fp) {
    int p0 = wp * 64 + fp * 16 + g * 4;
    float4 bv = *(const float4*)(bias + p0);
    #pragma unroll
    for (int fq = 0; fq < 4; ++fq) {
      int q = wq * 64 + fq * 16 + lr;
      float4 rv = *(const float4*)(recv + (size_t)q * HH + p0);
      float4 ov;
      ov.x = rv.x + gate * (acc[fp][fq][0] + bv.x);
      ov.y = rv.y + gate * (acc[fp][fq][1] + bv.y);
      ov.z = rv.z + gate * (acc[fp][fq][2] + bv.z);
      ov.w = rv.w + gate * (acc[fp][fq][3] + bv.w);
      *(float4*)(outp + (size_t)q * HH + p0) = ov;
    }
  }
}

// Full K-or-V path for one (layer, 128-row tile)
__device__ __forceinline__ void do_path(
    u16* sH, u16* sA, u16* sW, u16* sX,
    const float* __restrict__ recv_blk, const float* __restrict__ shar_blk,
    const u16* __restrict__ w1T, const u16* __restrict__ w2T,
    const u16* __restrict__ fw1T, const u16* __restrict__ fw2T,
    const float* __restrict__ b1, const float* __restrict__ b2,
    const float* __restrict__ fb1, const float* __restrict__ fb2,
    const float* __restrict__ ewl, float gate, float* __restrict__ outp,
    int tid, int wp, int wq, int lr, int g)
{
  f32x4 agg[4][4];
  zero44(agg);
  float sS = 0.f;
  // ---- align: agg += (ew_n/N) * MLP(sharer_n); scale folded into relu output,
  //      agg accumulated across n directly in the MFMA C operand.
  for (int n = 0; n < NN; ++n) {
    float sn = ewl[n] * 0.25f;
    sS += sn;
    f32x4 h[4][4];
    zero44(h);
    gemm_block<true >(h, w1T, 256, shar_blk + (size_t)n * RPL * HH, nullptr,
                      sW, sX, tid, wp, wq, lr, g);
    epi_store(sH, h, b1, 1.f, sn, true, wp, wq, lr, g);      // sH = sn*relu(h+b1)
    gemm_block<false>(agg, w2T, 256, nullptr, sH, sW, sX, tid, wp, wq, lr, g);
  }
  epi_store(sA, agg, b2, sS, 1.f, false, wp, wq, lr, g);     // sA = agg + sS*b2
  // ---- fuse: delta = MLP(concat(recv, agg)); out = recv + gate*delta
  f32x4 h[4][4];
  zero44(h);
  gemm_block<true >(h, fw1T,       512, recv_blk, nullptr, sW, sX, tid, wp, wq, lr, g);
  gemm_block<false>(h, fw1T + 256, 512, nullptr,  sA,      sW, sX, tid, wp, wq, lr, g);
  epi_store(sH, h, fb1, 1.f, 1.f, true, wp, wq, lr, g);
  f32x4 d[4][4];
  zero44(d);
  gemm_block<false>(d, fw2T, 256, nullptr, sH, sW, sX, tid, wp, wq, lr, g);
  epi_out(d, fb2, recv_blk, outp, gate, wp, wq, lr, g);
}

__global__ __launch_bounds__(512) void CacheFuser_73873437491748_kernel(
    const float* __restrict__ recv_k, const float* __restrict__ recv_v,
    const float* __restrict__ shar_k, const float* __restrict__ shar_v,
    const float* __restrict__ ew, const float* __restrict__ alpha,
    const float* __restrict__ ak_b1, const float* __restrict__ ak_b2,
    const float* __restrict__ av_b1, const float* __restrict__ av_b2,
    const float* __restrict__ fk_b1, const float* __restrict__ fk_b2,
    const float* __restrict__ fv_b1, const float* __restrict__ fv_b2,
    const u16* __restrict__ wt, float* __restrict__ out)
{
  __shared__ u16 sH[BM * HH];      // hidden, swizzled (idx ^= (q&7)<<3)
  __shared__ u16 sA[BM * HH];      // agg, swizzled
  __shared__ u16 sW[HH * WST];     // W^T k-tile, padded stride 40
  __shared__ u16 sX[BM * WST];     // streamed act k-tile, padded stride 40
  // total LDS = (32768+32768+10240+5120)*2 = 161792 B (<= 163840)

  const int l   = blockIdx.x >> 6;
  const int t64 = blockIdx.x & 63;
  const int tid = threadIdx.x;
  const int w = tid >> 6, lane = tid & 63, lr = lane & 15, g = lane >> 4;
  const int wp = w & 3, wq = w >> 2;

  const size_t rowStart = (size_t)t64 * BM;
  const float* rkb = recv_k + ((size_t)l * RPL + rowStart) * HH;
  const float* rvb = recv_v + ((size_t)l * RPL + rowStart) * HH;
  const float* skb = shar_k + ((size_t)l * NN * RPL + rowStart) * HH;
  const float* svb = shar_v + ((size_t)l * NN * RPL + rowStart) * HH;
  const float gate = 1.f / (1.f + expf(-2.f * alpha[l]));   // sigmoid(alpha/0.5)
  const float* ewl = ew + l * NN;
  float* outk = out + ((size_t)l * RPL + rowStart) * HH;
  float* outv = out + (((size_t)LL + l) * RPL + rowStart) * HH;

  do_path(sH, sA, sW, sX, rkb, skb,
          wt + OFF_AKW1 + (size_t)l * 65536, wt + OFF_AKW2 + (size_t)l * 65536,
          wt + OFF_FKW1 + (size_t)l * 131072, wt + OFF_FKW2 + (size_t)l * 65536,
          ak_b1 + l * HH, ak_b2 + l * HH, fk_b1 + l * HH, fk_b2 + l * HH,
          ewl, gate, outk, tid, wp, wq, lr, g);
  do_path(sH, sA, sW, sX, rvb, svb,
          wt + OFF_AVW1 + (size_t)l * 65536, wt + OFF_AVW2 + (size_t)l * 65536,
          wt + OFF_FVW1 + (size_t)l * 131072, wt + OFF_FVW2 + (size_t)l * 65536,
          av_b1 + l * HH, av_b2 + l * HH, fv_b1 + l * HH, fv_b2 + l * HH,
          ewl, gate, outv, tid, wp, wq, lr, g);
}

extern "C" void kernel_launch(void* const* d_in, const int* in_sizes, int n_in,
                              void* d_out, int out_size, void* d_ws, size_t ws_size,
                              hipStream_t stream)
{
  const float* recv_k = (const float*)d_in[0];
  const float* recv_v = (const float*)d_in[1];
  const float* shar_k = (const float*)d_in[2];
  const float* shar_v = (const float*)d_in[3];
  const float* ew     = (const float*)d_in[4];
  const float* alpha  = (const float*)d_in[5];
  const float* ak_w1 = (const float*)d_in[6];  const float* ak_b1 = (const float*)d_in[7];
  const float* ak_w2 = (const float*)d_in[8];  const float* ak_b2 = (const float*)d_in[9];
  const float* av_w1 = (const float*)d_in[10]; const float* av_b1 = (const float*)d_in[11];
  const float* av_w2 = (const float*)d_in[12]; const float* av_b2 = (const float*)d_in[13];
  const float* fk_w1 = (const float*)d_in[14]; const float* fk_b1 = (const float*)d_in[15];
  const float* fk_w2 = (const float*)d_in[16]; const float* fk_b2 = (const float*)d_in[17];
  const float* fv_w1 = (const float*)d_in[18]; const float* fv_b1 = (const float*)d_in[19];
  const float* fv_w2 = (const float*)d_in[20]; const float* fv_b2 = (const float*)d_in[21];
  u16* wt = (u16*)d_ws;          // needs 10485760 B of workspace
  float* outp = (float*)d_out;

  prep_wt_k<<<dim3(128, 8, 8), dim3(256), 0, stream>>>(
      ak_w1, ak_w2, av_w1, av_w2, fk_w1, fk_w2, fv_w1, fv_w2, wt);

  CacheFuser_73873437491748_kernel<<<dim3(512), dim3(512), 0, stream>>>(
      recv_k, recv_v, shar_k, shar_v, ew, alpha,
      ak_b1, ak_b2, av_b1, av_b2, fk_b1, fk_b2, fv_b1, fv_b2, wt, outp);
}